// Round 8
// baseline (1390.413 us; speedup 1.0000x reference)
//
#include <hip/hip_runtime.h>

typedef _Float16 f16;
typedef _Float16 f16x4 __attribute__((ext_vector_type(4)));
typedef _Float16 f16x8 __attribute__((ext_vector_type(8)));
typedef float f32x4 __attribute__((ext_vector_type(4)));

#define N_ROWS 500000
#define EPS_LOG 1e-7f
#define EPS_LN  1e-5f

// ws layout (819200 bytes total, footprint proven safe):
//   f16 idx [0, 10240)      : W1p [256][40], W1p[j][k]=W1[j][k] (k<39), k=39 -> 0
//   bytes [20480, 32768)    : f32 cst block:
//       cst[0..256)   = w8g[j] = W8[j]*gamma[j]
//       cst[256]      = s8  = sum_j w8g[j]
//       cst[257]      = cb8 = beta@W8^T + b8
//       cst[1536+li*256+j] = bb[li][j] = beta@W^T + b   (li=0..5 -> layers 2..7)
//   f16 idx [16384, 409600) : Wg layers 2..7 SLAB-PERMUTED:
//       idx = 16384 + li*65536 + kt*8192 + kgrp*2048 + j*8 + e
//       value = W[j][k]*gamma[k],  k = kt*32 + kgrp*8 + e
#define CST_BYTE_OFF 20480

// ---------------- prep ----------------
__global__ void prep_kernel(const float* __restrict__ W1,
                            const float* __restrict__ W2, const float* __restrict__ W3,
                            const float* __restrict__ W4, const float* __restrict__ W5,
                            const float* __restrict__ W6, const float* __restrict__ W7,
                            const float* __restrict__ W8, const float* __restrict__ b8,
                            const float* __restrict__ b2, const float* __restrict__ b3,
                            const float* __restrict__ b4, const float* __restrict__ b5,
                            const float* __restrict__ b6, const float* __restrict__ b7,
                            const float* __restrict__ gamma, const float* __restrict__ beta,
                            f16* __restrict__ ws) {
  float* cstF = (float*)((char*)ws + CST_BYTE_OFF);
  int idx = blockIdx.x * 256 + threadIdx.x;
  if (idx < 10240) {            // W1p [256][40]
    int j = idx / 40, k = idx - j * 40;
    ws[idx] = (f16)((k < 39) ? W1[j * 39 + k] : 0.0f);
  } else if (idx < 16384) {
    // cst region lives at bytes [20480,32768) — written below
  } else if (idx < 409600) {    // Wg = W*gamma, slab-permuted for LDS staging
    int o = idx - 16384;
    int li = o >> 16;  o &= 65535;
    const float* W = (li == 0) ? W2 : (li == 1) ? W3 : (li == 2) ? W4
                   : (li == 3) ? W5 : (li == 4) ? W6 : W7;
    int e = o & 7, j = (o >> 3) & 255, kgrp = (o >> 11) & 3, kt = o >> 13;
    int k = kt * 32 + kgrp * 8 + e;
    ws[idx] = (f16)(W[j * 256 + k] * gamma[k]);
  } else if (idx < 411136) {    // bb[li][j] = beta@W^T + b
    int o = idx - 409600;
    int li = o >> 8, j = o & 255;
    const float* W = (li == 0) ? W2 : (li == 1) ? W3 : (li == 2) ? W4
                   : (li == 3) ? W5 : (li == 4) ? W6 : W7;
    const float* b = (li == 0) ? b2 : (li == 1) ? b3 : (li == 2) ? b4
                   : (li == 3) ? b5 : (li == 4) ? b6 : b7;
    float bb = 0.f;
    for (int k = 0; k < 256; ++k) bb = fmaf(W[j * 256 + k], beta[k], bb);
    cstF[1536 + li * 256 + j] = bb + b[j];
  } else if (idx < 411392) {    // w8g
    int j = idx - 411136;
    cstF[j] = W8[j] * gamma[j];
  } else if (idx == 411392) {   // s8, cb8
    float s8 = 0.f, cb = 0.f;
    for (int k = 0; k < 256; ++k) {
      float w = W8[k];
      s8 = fmaf(w, gamma[k], s8);
      cb = fmaf(w, beta[k], cb);
    }
    cstF[256] = s8;
    cstF[257] = cb + b8[0];
  }
}

// ---------------- fused MLP: swapped-operand MFMA (D = W · z^T) ----------------
// 256 threads = 4 waves; 128 rows/block; wave owns rows [wid*32, wid*32+32).
// All hbuf traffic wave-private at row-stride 256 (r5-proven race-free).
// MFMA: A = W fragments (slab, lane&15 = feature j), B = z^T (lane&15 = datarow),
// D[feature][datarow]: lane holds 4 CONSECUTIVE FEATURES of one row -> b64 z-store,
// scalar per-row stats (1 in-lane sum + 2 shuffles), f32x4 bias loads.
// Layer 8 fused into layer-7 epilogue (in-register dot with w8g).
__global__ __launch_bounds__(256, 1)
void mlp_kernel(const float* __restrict__ x, const f16* __restrict__ wsw,
                const float* __restrict__ b1, float* __restrict__ out) {
  __shared__ __attribute__((aligned(16))) f16 hbuf[128 * 256];   // 64 KB
  __shared__ __attribute__((aligned(16))) f16 wslab[8192];       // 16 KB

  const float* cstF = (const float*)((const char*)wsw + CST_BYTE_OFF);
  const int t = threadIdx.x;
  const int lane = t & 63;
  const int wid = t >> 6;
  const int lm = lane & 15;
  const int lg = lane >> 4;
  const long rowbase = (long)blockIdx.x * 128;
  const int R0 = wid * 32;                 // wave's row band [R0, R0+32)
  const int row0 = R0 + lm;                // tile rt=0 datarow for this lane
  const int row1 = R0 + 16 + lm;           // tile rt=1 datarow
  const int sw0 = (row0 & 7) << 3;         // z-read swizzle (== (lm&7)<<3)
  const int sw1 = (row1 & 7) << 3;

  // in-flight slab chunks (named regs; no runtime-indexed arrays)
  f16x8 ld0, ld1, ld2, ld3;
  auto slab_load = [&](const f16* g) {
    ld0 = *(const f16x8*)(g + (0 * 256 + t) * 8);
    ld1 = *(const f16x8*)(g + (1 * 256 + t) * 8);
    ld2 = *(const f16x8*)(g + (2 * 256 + t) * 8);
    ld3 = *(const f16x8*)(g + (3 * 256 + t) * 8);
  };
  auto slab_write = [&]() {
    *(f16x8*)&wslab[(0 * 256 + t) * 8] = ld0;
    *(f16x8*)&wslab[(1 * 256 + t) * 8] = ld1;
    *(f16x8*)&wslab[(2 * 256 + t) * 8] = ld2;
    *(f16x8*)&wslab[(3 * 256 + t) * 8] = ld3;
  };

  const f16* WgBase = wsw + 16384;
  slab_load(WgBase);                       // layer-2 slab 0 in flight

  // ---- input fill (wave-private, stride 256, features 0..63, zero-padded) ----
  #pragma unroll 1
  for (int i = 0; i < 32; ++i) {
    int r = R0 + i;
    long gr = rowbase + r;
    float tv = 0.0f;
    if (lane < 39) {
      float xv = (gr < N_ROWS) ? x[gr * 39 + lane] : 1.0f;
      tv = 0.1f * __logf(xv + EPS_LOG);
    }
    hbuf[r * 256 + (lane ^ ((r & 7) << 3))] = (f16)tv;
  }

  f32x4 acc0[16], acc1[16];

  // epilogue, one 16-row tile: v = acc + cvec[feature]; a = act(v); per-row
  // stats; store z = (a-mu)*is as f16x4 (4 consecutive features, one b64).
  // Lane (lg,lm): acc[jt][i] = feature jt*16+lg*4+i, datarow R0+rt*16+lm.
  auto do_tile = [&](f32x4* acc, int rt, bool tanh_act, const float* cvec) {
    float nm = 0.f, nq = 0.f;
    #pragma unroll
    for (int jt = 0; jt < 16; ++jt) {
      f32x4 c4 = *(const f32x4*)&cvec[jt * 16 + lg * 4];
      #pragma unroll
      for (int i = 0; i < 4; ++i) {
        float v = acc[jt][i] + c4[i];
        float a;
        if (tanh_act) {
          float e2 = __expf(2.f * v);
          a = 1.f - 2.f / (e2 + 1.f);
        } else {
          a = (v > 0.f) ? v : (__expf(v) - 1.f);
        }
        acc[jt][i] = a;
        nm += a;
        nq = fmaf(a, a, nq);
      }
    }
    nm += __shfl_xor(nm, 16, 64);  nq += __shfl_xor(nq, 16, 64);
    nm += __shfl_xor(nm, 32, 64);  nq += __shfl_xor(nq, 32, 64);
    float mu = nm * (1.f / 256.f);
    float is = rsqrtf(nq * (1.f / 256.f) - mu * mu + EPS_LN);
    int row = R0 + rt * 16 + lm;
    int sw = (row & 7) << 3;
    #pragma unroll
    for (int jt = 0; jt < 16; ++jt) {
      f16x4 z4;
      #pragma unroll
      for (int i = 0; i < 4; ++i) z4[i] = (f16)((acc[jt][i] - mu) * is);
      *(f16x4*)&hbuf[row * 256 + ((jt * 16 + lg * 4) ^ sw)] = z4;
    }
  };

  // layer-7 epilogue fused with layer 8: out[row] = is*(dot - mu*s8) + cb8
  auto final_tile = [&](f32x4* acc, int rt) {
    const float* bb7 = cstF + 1536 + 5 * 256;
    float s8 = cstF[256], cb8 = cstF[257];
    float nm = 0.f, nq = 0.f, dt = 0.f;
    #pragma unroll
    for (int jt = 0; jt < 16; ++jt) {
      f32x4 c4 = *(const f32x4*)&bb7[jt * 16 + lg * 4];
      f32x4 w4 = *(const f32x4*)&cstF[jt * 16 + lg * 4];
      #pragma unroll
      for (int i = 0; i < 4; ++i) {
        float v = acc[jt][i] + c4[i];
        float a = (v > 0.f) ? v : (__expf(v) - 1.f);
        nm += a;
        nq = fmaf(a, a, nq);
        dt = fmaf(a, w4[i], dt);
      }
    }
    nm += __shfl_xor(nm, 16, 64);  nq += __shfl_xor(nq, 16, 64);
    dt += __shfl_xor(dt, 16, 64);
    nm += __shfl_xor(nm, 32, 64);  nq += __shfl_xor(nq, 32, 64);
    dt += __shfl_xor(dt, 32, 64);
    float mu = nm * (1.f / 256.f);
    float is = rsqrtf(nq * (1.f / 256.f) - mu * mu + EPS_LN);
    if (lane < 16) {
      long gr = rowbase + R0 + rt * 16 + lm;
      if (gr < N_ROWS) out[gr] = fmaf(is, dt - mu * s8, cb8);
    }
  };

  // ================= layer 1: z1 = LN-norm(tanh(t @ W1^T + b1)), K=64 =============
  {
    #pragma unroll
    for (int i = 0; i < 16; ++i) { acc0[i] = (f32x4){0,0,0,0}; acc1[i] = (f32x4){0,0,0,0}; }
    #pragma unroll
    for (int kt = 0; kt < 2; ++kt) {
      f16x8 bv0 = *(const f16x8*)&hbuf[row0 * 256 + ((kt * 32 + lg * 8) ^ sw0)];
      f16x8 bv1 = *(const f16x8*)&hbuf[row1 * 256 + ((kt * 32 + lg * 8) ^ sw1)];
      #pragma unroll
      for (int jt = 0; jt < 16; ++jt) {
        int j40 = (jt * 16 + lm) * 40;
        f16x8 af = 0;
        if (kt == 0)       af = *(const f16x8*)&wsw[j40 + lg * 8];
        else if (lg == 0)  af = *(const f16x8*)&wsw[j40 + 32];
        acc0[jt] = __builtin_amdgcn_mfma_f32_16x16x32_f16(af, bv0, acc0[jt], 0, 0, 0);
        acc1[jt] = __builtin_amdgcn_mfma_f32_16x16x32_f16(af, bv1, acc1[jt], 0, 0, 0);
      }
    }
    do_tile(acc0, 0, true, b1);
    do_tile(acc1, 1, true, b1);
  }

  // ================= layers 2..7 =================
  #pragma unroll 1
  for (int li = 0; li < 6; ++li) {
    #pragma unroll
    for (int i = 0; i < 16; ++i) { acc0[i] = (f32x4){0,0,0,0}; acc1[i] = (f32x4){0,0,0,0}; }
    #pragma unroll 1
    for (int kt = 0; kt < 8; ++kt) {
      slab_write();                          // regs (li,kt) -> wslab
      if (kt < 7)       slab_load(WgBase + li * 65536 + (kt + 1) * 8192);
      else if (li < 5)  slab_load(WgBase + (li + 1) * 65536);
      __syncthreads();   // READY: all waves' ds_writes visible
      {
        f16x8 bv0 = *(const f16x8*)&hbuf[row0 * 256 + ((kt * 32 + lg * 8) ^ sw0)];
        f16x8 bv1 = *(const f16x8*)&hbuf[row1 * 256 + ((kt * 32 + lg * 8) ^ sw1)];
        #pragma unroll
        for (int jt = 0; jt < 16; ++jt) {
          f16x8 af = *(const f16x8*)&wslab[lg * 2048 + (jt * 16 + lm) * 8];
          acc0[jt] = __builtin_amdgcn_mfma_f32_16x16x32_f16(af, bv0, acc0[jt], 0, 0, 0);
          acc1[jt] = __builtin_amdgcn_mfma_f32_16x16x32_f16(af, bv1, acc1[jt], 0, 0, 0);
        }
      }
      __syncthreads();   // FREE: all waves done reading slab (li,kt)
    }
    if (li < 5) {
      do_tile(acc0, 0, false, cstF + 1536 + li * 256);
      do_tile(acc1, 1, false, cstF + 1536 + li * 256);
    } else {
      final_tile(acc0, 0);
      final_tile(acc1, 1);
    }
  }
}

extern "C" void kernel_launch(void* const* d_in, const int* in_sizes, int n_in,
                              void* d_out, int out_size, void* d_ws, size_t ws_size,
                              hipStream_t stream) {
  const float* x  = (const float*)d_in[0];
  const float* W1 = (const float*)d_in[1];
  const float* b1 = (const float*)d_in[2];
  const float* W2 = (const float*)d_in[3];
  const float* b2 = (const float*)d_in[4];
  const float* W3 = (const float*)d_in[5];
  const float* b3 = (const float*)d_in[6];
  const float* W4 = (const float*)d_in[7];
  const float* b4 = (const float*)d_in[8];
  const float* W5 = (const float*)d_in[9];
  const float* b5 = (const float*)d_in[10];
  const float* W6 = (const float*)d_in[11];
  const float* b6 = (const float*)d_in[12];
  const float* W7 = (const float*)d_in[13];
  const float* b7 = (const float*)d_in[14];
  const float* W8 = (const float*)d_in[15];
  const float* b8 = (const float*)d_in[16];
  const float* gm = (const float*)d_in[17];
  const float* bt = (const float*)d_in[18];
  f16* ws = (f16*)d_ws;
  float* out = (float*)d_out;

  // max idx 411392 -> 1608 blocks
  prep_kernel<<<1608, 256, 0, stream>>>(W1, W2, W3, W4, W5, W6, W7, W8, b8,
                                        b2, b3, b4, b5, b6, b7, gm, bt, ws);

  int nblk = (N_ROWS + 127) / 128;   // 3907
  mlp_kernel<<<nblk, 256, 0, stream>>>(x, ws, b1, out);
}